// Round 5
// baseline (219.350 us; speedup 1.0000x reference)
//
#include <hip/hip_runtime.h>
#include <hip/hip_bf16.h>

#define V 50000
#define E 256
#define RADIUS 180
#define TAA_W (2 * RADIUS + 1)   // 361
#define BATCH 2048
#define CTX_L 200
#define NOPT 10

#define ISE_BLOCKS  (V / 16)                 // 3125 blocks, 16 rows each
#define CONV_BLOCKS 3125                     // each thread converts 4 float4
#define CONV_STRIDE (CONV_BLOCKS * 256)      // 800,000 float4 per round

typedef float  vf4 __attribute__((ext_vector_type(4)));

__device__ __forceinline__ unsigned short f2bf_rne(float f) {
    unsigned u = __float_as_uint(f);
    u += 0x7fffu + ((u >> 16) & 1u);         // round-to-nearest-even
    return (unsigned short)(u >> 16);
}
__device__ __forceinline__ unsigned pack_bf16(float a, float b) {
    return (unsigned)f2bf_rne(a) | ((unsigned)f2bf_rne(b) << 16);
}
__device__ __forceinline__ float bf_lo(unsigned u) {
    return __uint_as_float(u << 16);
}
__device__ __forceinline__ float bf_hi(unsigned u) {
    return __uint_as_float(u & 0xffff0000u);
}

// Per-row inverse-sum-exp of taa_matrix. Bias dropped (softmax invariant to a
// per-row constant); no max pass (taa ~ uniform[0,1), exp cannot overflow).
// Block = 16 rows = 5776 contiguous floats (1444 float4, 16B-aligned):
// coalesced load+exp -> LDS, then 16 lanes per row strided-reduce + shfl tree.
__global__ __launch_bounds__(256) void taa_ise_kernel(
    const float* __restrict__ taa, float* __restrict__ inv)
{
    __shared__ float s_e[16 * TAA_W];        // 5776 floats = 23.1 KB
    const int tid = threadIdx.x;
    const float4* p = (const float4*)taa + (size_t)blockIdx.x * 1444;
#pragma unroll
    for (int k = 0; k < 6; ++k) {
        int j = tid + 256 * k;
        if (j < 1444) {
            float4 v = p[j];
            float* d = &s_e[4 * j];
            d[0] = __expf(v.x);
            d[1] = __expf(v.y);
            d[2] = __expf(v.z);
            d[3] = __expf(v.w);
        }
    }
    __syncthreads();
    const int r = tid >> 4;                  // row 0..15
    const int c = tid & 15;                  // lane-part 0..15
    const float* row = &s_e[r * TAA_W];
    float s = 0.f;
#pragma unroll
    for (int i = c; i < TAA_W; i += 16) s += row[i];
    for (int off = 1; off < 16; off <<= 1) s += __shfl_xor(s, off, 64);
    if (c == 0) inv[16 * blockIdx.x + r] = 1.0f / s;
}

// f32 -> bf16 compaction of context_emb_table into workspace.
// Nontemporal loads: the f32 table is read-once (main only touches btab),
// so don't let it evict taa/btab from L3.
__global__ __launch_bounds__(256) void conv_kernel(
    const float* __restrict__ ctx_tab, uint2* __restrict__ btab)
{
    const vf4* src = (const vf4*)ctx_tab;
    size_t base = (size_t)blockIdx.x * 256 + threadIdx.x;
#pragma unroll
    for (int r = 0; r < 4; ++r) {
        size_t i = base + (size_t)r * CONV_STRIDE;
        vf4 v = __builtin_nontemporal_load(src + i);
        uint2 o;
        o.x = pack_bf16(v.x, v.y);
        o.y = pack_bf16(v.z, v.w);
        btab[i] = o;
    }
}

// Main: one block (4 waves) per batch row b.
//  A) threads 0..199: w[l] = mask * exp(taa[ev][td]) * inv[ev]  -> LDS
//  B) wave ws owns l = ws+4k: gather bf16 embedding row (8B/lane, full 512B
//     row per wave per instruction), f32 accumulate, LDS combine.
//  C) wave-per-option dot(target_emb_row, hidden) -> f32 scores
template <int USE_BF16>
__global__ __launch_bounds__(256) void mce_taa_main_kernel(
    const int*   __restrict__ ctx,      // (B, L, 2) int32
    const int*   __restrict__ mt,       // (B, NOPT+1) int32
    const float* __restrict__ ctx_tab,  // (V, E) f32 (fallback path)
    const uint2* __restrict__ btab,     // (V, E) bf16 packed (fast path)
    const float* __restrict__ tgt_tab,  // (V, E) f32
    const float* __restrict__ taa,      // (V, 361) f32
    const float* __restrict__ inv,      // (V,) f32  (1 / sum-exp per row)
    float*       __restrict__ out)      // (B, NOPT) f32
{
    __shared__ int   s_ev[CTX_L];
    __shared__ float s_w[CTX_L];
    __shared__ float s_part[4 * E];
    __shared__ float s_hid[E];

    const int b   = blockIdx.x;
    const int tid = threadIdx.x;
    const int tgt_time = mt[b * (NOPT + 1) + NOPT];

    if (tid < CTX_L) {
        int2 ct = ((const int2*)ctx)[b * CTX_L + tid];
        int ev = ct.x, t = ct.y;
        int mask = (ev == -1) ? 0 : 1;
        ev = mask ? ev : 0;
        if (ev < 0) ev += V;   // jax negative-index wrap safety
        int td = t - tgt_time + RADIUS;
        td = min(max(td, 0), 2 * RADIUS);
        float x = taa[(size_t)ev * TAA_W + td];
        s_ev[tid] = ev;
        s_w[tid]  = mask ? __expf(x) * inv[ev] : 0.f;
    }
    __syncthreads();

    const int ws   = tid >> 6;   // wave slot 0..3
    const int lane = tid & 63;

    float a0 = 0.f, a1 = 0.f, a2 = 0.f, a3 = 0.f;
    if (USE_BF16) {
#pragma unroll 10
        for (int l0 = 0; l0 < CTX_L; l0 += 4) {
            int   l  = l0 + ws;
            int   ev = s_ev[l];
            float w  = s_w[l];
            uint2 u  = btab[(size_t)ev * (E / 4) + lane];   // 4 bf16 = 8B/lane
            a0 = fmaf(bf_lo(u.x), w, a0);
            a1 = fmaf(bf_hi(u.x), w, a1);
            a2 = fmaf(bf_lo(u.y), w, a2);
            a3 = fmaf(bf_hi(u.y), w, a3);
        }
    } else {
        const float4* tab4 = (const float4*)ctx_tab;
#pragma unroll 10
        for (int l0 = 0; l0 < CTX_L; l0 += 4) {
            int    l  = l0 + ws;
            int    ev = s_ev[l];
            float  w  = s_w[l];
            float4 u  = tab4[(size_t)ev * (E / 4) + lane];
            a0 = fmaf(u.x, w, a0);
            a1 = fmaf(u.y, w, a1);
            a2 = fmaf(u.z, w, a2);
            a3 = fmaf(u.w, w, a3);
        }
    }
    {
        float* p = &s_part[ws * E + lane * 4];
        p[0] = a0; p[1] = a1; p[2] = a2; p[3] = a3;
    }
    __syncthreads();
    s_hid[tid] = s_part[tid] + s_part[E + tid] + s_part[2 * E + tid] + s_part[3 * E + tid];
    __syncthreads();

    const float4* ttab4 = (const float4*)tgt_tab;
    for (int n = ws; n < NOPT; n += 4) {
        int tg = mt[b * (NOPT + 1) + n];
        if (tg < 0) tg += V;
        float4 u = ttab4[(size_t)tg * (E / 4) + lane];
        float p = u.x * s_hid[lane * 4 + 0]
                + u.y * s_hid[lane * 4 + 1]
                + u.z * s_hid[lane * 4 + 2]
                + u.w * s_hid[lane * 4 + 3];
        for (int off = 32; off > 0; off >>= 1) p += __shfl_xor(p, off, 64);
        if (lane == 0) out[b * NOPT + n] = p;
    }
}

extern "C" void kernel_launch(void* const* d_in, const int* in_sizes, int n_in,
                              void* d_out, int out_size, void* d_ws, size_t ws_size,
                              hipStream_t stream) {
    const int*   ctx     = (const int*)d_in[0];
    const int*   mt      = (const int*)d_in[1];
    const float* ctx_tab = (const float*)d_in[2];
    const float* tgt_tab = (const float*)d_in[3];
    const float* taa     = (const float*)d_in[4];
    // d_in[5] = taa_bias: per-row constant inside softmax -> mathematically irrelevant
    float* out = (float*)d_out;

    float* inv  = (float*)d_ws;                          // 200 KB
    uint2* btab = (uint2*)((char*)d_ws + (256 << 10));   // 25.6 MB bf16 table
    const size_t need = (256 << 10) + (size_t)V * E * 2;
    const int use_bf16 = (ws_size >= need) ? 1 : 0;

    if (use_bf16) conv_kernel<<<CONV_BLOCKS, 256, 0, stream>>>(ctx_tab, btab);
    taa_ise_kernel<<<ISE_BLOCKS, 256, 0, stream>>>(taa, inv);
    if (use_bf16) {
        mce_taa_main_kernel<1><<<BATCH, 256, 0, stream>>>(
            ctx, mt, ctx_tab, btab, tgt_tab, taa, inv, out);
    } else {
        mce_taa_main_kernel<0><<<BATCH, 256, 0, stream>>>(
            ctx, mt, ctx_tab, btab, tgt_tab, taa, inv, out);
    }
}

// Round 6
// 214.888 us; speedup vs baseline: 1.0208x; 1.0208x over previous
//
#include <hip/hip_runtime.h>
#include <hip/hip_bf16.h>

#define V 50000
#define E 256
#define RADIUS 180
#define TAA_W (2 * RADIUS + 1)   // 361
#define BATCH 2048
#define CTX_L 200
#define NOPT 10

#define ISE_BLOCKS  (V / 16)                 // 3125 blocks, 16 rows each
#define CONV_BLOCKS 3125                     // each thread converts 4 float4
#define CONV_STRIDE (CONV_BLOCKS * 256)      // 800,000 float4 per round

typedef float vf4 __attribute__((ext_vector_type(4)));

__device__ __forceinline__ unsigned short f2bf_rne(float f) {
    unsigned u = __float_as_uint(f);
    u += 0x7fffu + ((u >> 16) & 1u);         // round-to-nearest-even
    return (unsigned short)(u >> 16);
}
__device__ __forceinline__ unsigned pack_bf16(float a, float b) {
    return (unsigned)f2bf_rne(a) | ((unsigned)f2bf_rne(b) << 16);
}
__device__ __forceinline__ float bf_lo(unsigned u) {
    return __uint_as_float(u << 16);
}
__device__ __forceinline__ float bf_hi(unsigned u) {
    return __uint_as_float(u & 0xffff0000u);
}

// Fused prep, one dispatch so the two HBM streams overlap:
//  blocks [0, ISE_BLOCKS): per-row inverse-sum-exp of taa_matrix (LDS method).
//    Bias dropped (softmax invariant per-row constant); no max pass (taa is
//    uniform[0,1), exp cannot overflow). 16 rows = 1444 contiguous float4:
//    coalesced load+exp -> LDS, 16 lanes/row strided reduce + shfl tree.
//  blocks [ISE_BLOCKS, +CONV_BLOCKS): f32 -> bf16 compaction of ctx_emb_table
//    (nontemporal f32 loads: read-once; keep L3 for taa/btab which get re-read).
__global__ __launch_bounds__(256) void prep_fused_kernel(
    const float* __restrict__ taa, const float* __restrict__ ctx_tab,
    float* __restrict__ inv, uint2* __restrict__ btab, int do_conv)
{
    __shared__ float s_e[16 * TAA_W];        // 23.1 KB
    const int tid = threadIdx.x;
    const int blk = blockIdx.x;
    if (blk < ISE_BLOCKS) {
        const float4* p = (const float4*)taa + (size_t)blk * 1444;
#pragma unroll
        for (int k = 0; k < 6; ++k) {
            int j = tid + 256 * k;
            if (j < 1444) {
                float4 v = p[j];
                float* d = &s_e[4 * j];
                d[0] = __expf(v.x);
                d[1] = __expf(v.y);
                d[2] = __expf(v.z);
                d[3] = __expf(v.w);
            }
        }
        __syncthreads();
        const int r = tid >> 4;              // row 0..15
        const int c = tid & 15;              // part 0..15
        const float* row = &s_e[r * TAA_W];
        float s = 0.f;
#pragma unroll
        for (int i = c; i < TAA_W; i += 16) s += row[i];
        for (int off = 1; off < 16; off <<= 1) s += __shfl_xor(s, off, 64);
        if (c == 0) inv[16 * blk + r] = 1.0f / s;
    } else if (do_conv) {
        const vf4* src = (const vf4*)ctx_tab;
        size_t base = (size_t)(blk - ISE_BLOCKS) * 256 + tid;
#pragma unroll
        for (int r = 0; r < 4; ++r) {
            size_t i = base + (size_t)r * CONV_STRIDE;
            vf4 v = __builtin_nontemporal_load(src + i);
            uint2 o;
            o.x = pack_bf16(v.x, v.y);
            o.y = pack_bf16(v.z, v.w);
            btab[i] = o;
        }
    }
}

// Main: one block (4 waves) per batch row b.
//  A) threads 0..199: w[l] = mask * exp(taa[ev][td]) * inv[ev]  -> LDS
//  B) wave ws owns l = ws+4k: gather bf16 embedding rows (8B/lane, full 512B
//     row per wave per instr), 2 rows in flight per iteration, f32 accumulate.
//  C) wave-per-option dot(target_emb_row, hidden) -> f32 scores
template <int USE_BF16>
__global__ __launch_bounds__(256) void mce_taa_main_kernel(
    const int*   __restrict__ ctx,      // (B, L, 2) int32
    const int*   __restrict__ mt,       // (B, NOPT+1) int32
    const float* __restrict__ ctx_tab,  // (V, E) f32 (fallback path)
    const uint2* __restrict__ btab,     // (V, E) bf16 packed (fast path)
    const float* __restrict__ tgt_tab,  // (V, E) f32
    const float* __restrict__ taa,      // (V, 361) f32
    const float* __restrict__ inv,      // (V,) f32  (1 / sum-exp per row)
    float*       __restrict__ out)      // (B, NOPT) f32
{
    __shared__ int   s_ev[CTX_L];
    __shared__ float s_w[CTX_L];
    __shared__ float s_part[4 * E];
    __shared__ float s_hid[E];

    const int b   = blockIdx.x;
    const int tid = threadIdx.x;
    const int tgt_time = mt[b * (NOPT + 1) + NOPT];

    if (tid < CTX_L) {
        int2 ct = ((const int2*)ctx)[b * CTX_L + tid];
        int ev = ct.x, t = ct.y;
        int mask = (ev == -1) ? 0 : 1;
        ev = mask ? ev : 0;
        if (ev < 0) ev += V;   // jax negative-index wrap safety
        int td = t - tgt_time + RADIUS;
        td = min(max(td, 0), 2 * RADIUS);
        float x = taa[(size_t)ev * TAA_W + td];
        s_ev[tid] = ev;
        s_w[tid]  = mask ? __expf(x) * inv[ev] : 0.f;
    }
    __syncthreads();

    const int ws   = tid >> 6;   // wave slot 0..3
    const int lane = tid & 63;

    float a0 = 0.f, a1 = 0.f, a2 = 0.f, a3 = 0.f;
    if (USE_BF16) {
#pragma unroll 5
        for (int l0 = 0; l0 < CTX_L; l0 += 8) {
            int   la  = l0 + ws,      lb  = l0 + 4 + ws;
            int   eva = s_ev[la],     evb = s_ev[lb];
            float wa  = s_w[la],      wb  = s_w[lb];
            uint2 ua  = btab[(size_t)eva * (E / 4) + lane];
            uint2 ub  = btab[(size_t)evb * (E / 4) + lane];
            a0 = fmaf(bf_lo(ua.x), wa, a0);
            a1 = fmaf(bf_hi(ua.x), wa, a1);
            a2 = fmaf(bf_lo(ua.y), wa, a2);
            a3 = fmaf(bf_hi(ua.y), wa, a3);
            a0 = fmaf(bf_lo(ub.x), wb, a0);
            a1 = fmaf(bf_hi(ub.x), wb, a1);
            a2 = fmaf(bf_lo(ub.y), wb, a2);
            a3 = fmaf(bf_hi(ub.y), wb, a3);
        }
    } else {
        const float4* tab4 = (const float4*)ctx_tab;
#pragma unroll 5
        for (int l0 = 0; l0 < CTX_L; l0 += 4) {
            int    l  = l0 + ws;
            int    ev = s_ev[l];
            float  w  = s_w[l];
            float4 u  = tab4[(size_t)ev * (E / 4) + lane];
            a0 = fmaf(u.x, w, a0);
            a1 = fmaf(u.y, w, a1);
            a2 = fmaf(u.z, w, a2);
            a3 = fmaf(u.w, w, a3);
        }
    }
    {
        float* p = &s_part[ws * E + lane * 4];
        p[0] = a0; p[1] = a1; p[2] = a2; p[3] = a3;
    }
    __syncthreads();
    s_hid[tid] = s_part[tid] + s_part[E + tid] + s_part[2 * E + tid] + s_part[3 * E + tid];
    __syncthreads();

    const float4* ttab4 = (const float4*)tgt_tab;
    for (int n = ws; n < NOPT; n += 4) {
        int tg = mt[b * (NOPT + 1) + n];
        if (tg < 0) tg += V;
        float4 u = ttab4[(size_t)tg * (E / 4) + lane];
        float p = u.x * s_hid[lane * 4 + 0]
                + u.y * s_hid[lane * 4 + 1]
                + u.z * s_hid[lane * 4 + 2]
                + u.w * s_hid[lane * 4 + 3];
        for (int off = 32; off > 0; off >>= 1) p += __shfl_xor(p, off, 64);
        if (lane == 0) out[b * NOPT + n] = p;
    }
}

extern "C" void kernel_launch(void* const* d_in, const int* in_sizes, int n_in,
                              void* d_out, int out_size, void* d_ws, size_t ws_size,
                              hipStream_t stream) {
    const int*   ctx     = (const int*)d_in[0];
    const int*   mt      = (const int*)d_in[1];
    const float* ctx_tab = (const float*)d_in[2];
    const float* tgt_tab = (const float*)d_in[3];
    const float* taa     = (const float*)d_in[4];
    // d_in[5] = taa_bias: per-row constant inside softmax -> mathematically irrelevant
    float* out = (float*)d_out;

    float* inv  = (float*)d_ws;                          // 200 KB
    uint2* btab = (uint2*)((char*)d_ws + (256 << 10));   // 25.6 MB bf16 table
    const size_t need = (256 << 10) + (size_t)V * E * 2;
    const int use_bf16 = (ws_size >= need) ? 1 : 0;

    prep_fused_kernel<<<ISE_BLOCKS + (use_bf16 ? CONV_BLOCKS : 0), 256, 0,
                        stream>>>(taa, ctx_tab, inv, btab, use_bf16);
    if (use_bf16) {
        mce_taa_main_kernel<1><<<BATCH, 256, 0, stream>>>(
            ctx, mt, ctx_tab, btab, tgt_tab, taa, inv, out);
    } else {
        mce_taa_main_kernel<0><<<BATCH, 256, 0, stream>>>(
            ctx, mt, ctx_tab, btab, tgt_tab, taa, inv, out);
    }
}